// Round 14
// baseline (241.993 us; speedup 1.0000x reference)
//
#include <hip/hip_runtime.h>
#include <hip/hip_bf16.h>

#define BATCH    256
#define NU       300
#define LIN      608
#define FILT     19
#define LPOOL    84
#define POOL     7
#define HID      100
#define NCLS     50
#define EPS      1e-5f
#define KP       96    // stage-2 K padded (84 -> 96)
#define NP       112   // stage-2 N padded (100 -> 112)
#define LDK      104   // LDS row stride (shorts) for MFMA tiles
#define WROW     104   // packed-W row stride (shorts)
#define WBROWS   320   // packed-W rows (300 + pad)
#define TCHUNK   112   // t per conv block = lcm(16,7)
#define MTN      19    // conv u-tiles (rows 0..303 cover u<300)
#define BH       128   // batches per k_mlp block

typedef __attribute__((ext_vector_type(8))) short short8;   // 8 bf16
typedef __attribute__((ext_vector_type(4))) float float4v;  // MFMA acc

__device__ __forceinline__ unsigned short f2bf(float f) {
    unsigned u = __float_as_uint(f);
    u += 0x7fffu + ((u >> 16) & 1u);       // round-to-nearest-even
    return (unsigned short)(u >> 16);
}
__device__ __forceinline__ float bf2f(unsigned short h) {
    return __uint_as_float(((unsigned)h) << 16);
}

// ---------------------------------------------------------------------------
// k_prep: (byte-identical to R13 — verified)
// ---------------------------------------------------------------------------
__global__ void k_prep(const float* __restrict__ w1, const float* __restrict__ x,
                       const float* __restrict__ b1, const float* __restrict__ g1,
                       const float* __restrict__ be1, const float* __restrict__ m1,
                       const float* __restrict__ v1,
                       unsigned short* __restrict__ Wbh,
                       unsigned short* __restrict__ Wbl,
                       unsigned int* __restrict__ xc,
                       float2* __restrict__ s1c1)
{
    const int idx = blockIdx.x * 256 + threadIdx.x;
    const int NW = WBROWS * WROW;               // 33280
    if (idx < NW) {
        const int u = idx / WROW, kk = idx - u * WROW;
        float wv = 0.f;
        if (u < NU && kk < 96) {
            const int c = kk / 24, tap = kk - 24 * c;
            if (tap < FILT) wv = w1[(u * 4 + c) * FILT + tap];
        }
        const unsigned short hi = f2bf(wv);
        Wbh[idx] = hi;
        Wbl[idx] = f2bf(wv - bf2f(hi));
    }
    const int j = idx - NW;
    if (j >= 0 && j < BATCH * 4 * LIN) {
        const float xv = x[j];
        const unsigned short hi = f2bf(xv);
        const unsigned short lo = f2bf(xv - bf2f(hi));
        xc[j] = (unsigned)hi | ((unsigned)lo << 16);
    }
    const int j2 = j - BATCH * 4 * LIN;
    if (j2 >= 0 && j2 < MTN * 16) {
        float2 v = {0.f, 0.f};
        if (j2 < NU) {
            const float s = g1[j2] * rsqrtf(v1[j2] + EPS);
            v.x = s;
            v.y = (b1[j2] - m1[j2]) * s + be1[j2];
        }
        s1c1[j2] = v;
    }
}

// ---------------------------------------------------------------------------
// k_conv7: conv(4->300,k=19)+bias+BN+exp+maxpool(7), bf16 MFMA implicit GEMM.
//   NUMERICS CHANGE vs conv6: acc = (Wh + Wl)*xh  (2 passes, W carried to
//   ~2^-18; only x-quantization error remains, same order as the ypool-bf16
//   term we already carry). Predicted absmax ~0.17 vs threshold 0.4725.
//   STRUCTURE: only Bh staged (Bl tile GONE) -> LDS 29.8 KB -> 5 blocks/CU
//   (launch_bounds 256,5); MFMA count -33%; main-loop LDS reads halved.
//   Wave-private paired u-tiles + transposed quarter-Cs as in conv6.
// ---------------------------------------------------------------------------
__global__ __launch_bounds__(256, 5)
void k_conv7(const unsigned short* __restrict__ Wbh,
             const unsigned short* __restrict__ Wbl,
             const unsigned int* __restrict__ xc,
             const float2* __restrict__ s1c1,
             unsigned short* __restrict__ ypool)
{
    __shared__ __align__(16) unsigned short Bh[TCHUNK * LDK];  // 23296 B
    __shared__ __align__(16) float Cs[4][TCHUNK * 4];          // 7168 B (per-wave)

    const int tid = threadIdx.x;
    const int b   = blockIdx.x;
    const int tc  = blockIdx.y;
    const int t0  = TCHUNK * tc;
    const int NT  = (tc == 5) ? 2 : 7;         // N-tiles (t) in this block

    // ---- stage B tile (im2col, hi only): row trow, kk = 24c + 8*third + j ----
    for (int i = tid; i < TCHUNK * 12; i += 256) {
        const int trow = i / 12;
        if (trow >= 16 * NT) continue;         // unused rows (tc==5)
        const int rem   = i - 12 * trow;
        const int c     = rem / 3;
        const int third = rem - 3 * c;
        const int kkb   = 24 * c + 8 * third;
        const int tt0   = t0 + trow + 8 * third;
        const unsigned int* src = xc + ((b * 4 + c) * LIN + tt0);

        unsigned int w[8];
        if (third < 2 && tt0 + 8 <= LIN) {     // all 8 taps valid & in range
            const uint4 v0 = *(const uint4*)(src);
            const uint4 v1 = *(const uint4*)(src + 4);
            w[0] = v0.x; w[1] = v0.y; w[2] = v0.z; w[3] = v0.w;
            w[4] = v1.x; w[5] = v1.y; w[6] = v1.z; w[7] = v1.w;
        } else {
#pragma unroll
            for (int j = 0; j < 8; ++j) {
                const int tap = 8 * third + j;
                const int tt  = tt0 + j;
                unsigned int v = 0;
                if (tap < FILT && tt < LIN) v = src[j];
                w[j] = v;
            }
        }
        short8 hv;
#pragma unroll
        for (int j = 0; j < 8; ++j) hv[j] = (short)(w[j] & 0xffffu);
        *(short8*)(&Bh[trow * LDK + kkb]) = hv;
    }
    __syncthreads();   // the ONLY block-wide barrier

    const int lane = tid & 63;
    const int n    = lane & 15;
    const int quad = lane >> 4;
    const int wave = tid >> 6;
    float* Csw = Cs[wave];          // wave-private transposed scratch [112][4]

    const int ep_ul = lane & 3;     // epilogue: u-row within quarter
    const int ep_p  = lane >> 2;    // epilogue: pool window 0..15

    // pair-units k: tiles (2k, 2k+1); k = wave, wave+4, wave+8 (k<10)
    for (int k = wave; k < 10; k += 4) {
        const int mt0 = 2 * k;
        const bool two = (mt0 + 1 < MTN);

        // ---- W fragments (hi & lo) for both tiles, from global (L2-hot) ----
        short8 a0h[3], a0l[3], a1h[3], a1l[3];
        {
            const unsigned short* wrh = Wbh + (size_t)(mt0 * 16 + n) * WROW;
            const unsigned short* wrl = Wbl + (size_t)(mt0 * 16 + n) * WROW;
#pragma unroll
            for (int s = 0; s < 3; ++s) {
                a0h[s] = *(const short8*)(wrh + 32 * s + 8 * quad);
                a0l[s] = *(const short8*)(wrl + 32 * s + 8 * quad);
            }
            const int m1r = two ? (mt0 + 1) : mt0;
            const unsigned short* wrh1 = Wbh + (size_t)(m1r * 16 + n) * WROW;
            const unsigned short* wrl1 = Wbl + (size_t)(m1r * 16 + n) * WROW;
#pragma unroll
            for (int s = 0; s < 3; ++s) {
                a1h[s] = *(const short8*)(wrh1 + 32 * s + 8 * quad);
                a1l[s] = *(const short8*)(wrl1 + 32 * s + 8 * quad);
            }
        }

        // ---- main loop: xh-frags read once per nt, used by BOTH tiles ----
        float4v acc[2][7];
#pragma unroll
        for (int t2 = 0; t2 < 2; ++t2)
#pragma unroll
            for (int nt = 0; nt < 7; ++nt)
                acc[t2][nt] = (float4v){0.f, 0.f, 0.f, 0.f};

#pragma unroll
        for (int nt = 0; nt < 7; ++nt) {
            if (nt < NT) {
                short8 bhf[3];
#pragma unroll
                for (int s = 0; s < 3; ++s)
                    bhf[s] = *(const short8*)(&Bh[(16 * nt + n) * LDK + 32 * s + 8 * quad]);
#pragma unroll
                for (int s = 0; s < 3; ++s)
                    acc[0][nt] = __builtin_amdgcn_mfma_f32_16x16x32_bf16(
                        a0h[s], bhf[s], acc[0][nt], 0, 0, 0);
#pragma unroll
                for (int s = 0; s < 3; ++s)
                    acc[0][nt] = __builtin_amdgcn_mfma_f32_16x16x32_bf16(
                        a0l[s], bhf[s], acc[0][nt], 0, 0, 0);
                if (two) {
#pragma unroll
                    for (int s = 0; s < 3; ++s)
                        acc[1][nt] = __builtin_amdgcn_mfma_f32_16x16x32_bf16(
                            a1h[s], bhf[s], acc[1][nt], 0, 0, 0);
#pragma unroll
                    for (int s = 0; s < 3; ++s)
                        acc[1][nt] = __builtin_amdgcn_mfma_f32_16x16x32_bf16(
                            a1l[s], bhf[s], acc[1][nt], 0, 0, 0);
                }
            }
        }

        // ---- wave-local epilogue per tile, 4 quarters of 4 u-rows ----
#pragma unroll
        for (int t2 = 0; t2 < 2; ++t2) {
            if (t2 == 1 && !two) break;
            const int mt = mt0 + t2;
#pragma unroll
            for (int qq = 0; qq < 4; ++qq) {
                __builtin_amdgcn_fence(__ATOMIC_ACQ_REL, "workgroup");
                if (quad == qq) {
#pragma unroll
                    for (int nt = 0; nt < 7; ++nt) {
                        if (nt < NT)
                            *(float4v*)(&Csw[(16 * nt + n) * 4]) = acc[t2][nt];
                    }
                }
                __builtin_amdgcn_fence(__ATOMIC_ACQ_REL, "workgroup");

                const int uglob = mt * 16 + 4 * qq + ep_ul;
                const int pg    = 16 * tc + ep_p;
                if (uglob < NU) {
                    unsigned short outv = 0;
                    if (pg < LPOOL) {
                        float mx = Csw[(7 * ep_p) * 4 + ep_ul];
#pragma unroll
                        for (int j = 1; j < 7; ++j)
                            mx = fmaxf(mx, Csw[(7 * ep_p + j) * 4 + ep_ul]);
                        const float2 sc = s1c1[uglob];
                        outv = f2bf(__expf(fmaf(mx, sc.x, sc.y)));
                    }
                    if (pg < KP)
                        ypool[((size_t)uglob * BATCH + b) * KP + pg] = outv;
                }
            }
        }
    }
}

// ---------------------------------------------------------------------------
// k_mlp v3: (byte-identical to R9-R13 — verified, pass)
// ---------------------------------------------------------------------------
__global__ __launch_bounds__(256, 3)
void k_mlp(const unsigned short* __restrict__ ypool,
           const float* __restrict__ w2, const float* __restrict__ b2,
           const float* __restrict__ g2, const float* __restrict__ be2,
           const float* __restrict__ m2, const float* __restrict__ v2,
           const float* __restrict__ w3, const float* __restrict__ b3,
           const float* __restrict__ g3, const float* __restrict__ be3,
           const float* __restrict__ m3, const float* __restrict__ v3,
           float* __restrict__ zbuf)
{
    __shared__ __align__(16) unsigned short As[NP * LDK];   // w2 tile 23296 B
    __shared__ __align__(16) unsigned short Bs[BH * LDK];   // y  tile 26624 B
    __shared__ __align__(16) float4 cs4[NP];                // (s2,c2,w3,0)

    const int tid = threadIdx.x;
    const int u   = blockIdx.x;
    const int b0  = blockIdx.y * BH;

    {
        const float* src = w2 + (size_t)u * HID * LPOOL;
        for (int c = tid; c < HID * (LPOOL / 4); c += 256) {
            const int o  = c / (LPOOL / 4);
            const int kc = (c % (LPOOL / 4)) * 4;
            const float4 v = *(const float4*)(src + o * LPOOL + kc);
            unsigned short* d = &As[o * LDK + kc];
            d[0] = f2bf(v.x); d[1] = f2bf(v.y); d[2] = f2bf(v.z); d[3] = f2bf(v.w);
        }
        for (int c = tid; c < HID * 6; c += 256) {            // k-pad [84,96)
            const int o = c / 6, kc = LPOOL + (c % 6) * 2;
            *(unsigned*)(&As[o * LDK + kc]) = 0;
        }
        for (int c = tid; c < (NP - HID) * (KP / 2); c += 256) { // o-pad rows
            const int o = HID + c / (KP / 2), kc = (c % (KP / 2)) * 2;
            *(unsigned*)(&As[o * LDK + kc]) = 0;
        }
    }
    {
        const unsigned short* ys = ypool + ((size_t)u * BATCH + b0) * KP;
        for (int c = tid; c < BH * (KP / 8); c += 256) {
            const int n  = c / (KP / 8);
            const int kc = (c % (KP / 8)) * 8;
            *(short8*)(&Bs[n * LDK + kc]) = *(const short8*)(ys + n * KP + kc);
        }
    }
    if (tid < NP) {
        float4 cv = {0.f, 0.f, 0.f, 0.f};
        if (tid < HID) {
            const int uo = u * HID + tid;
            const float s = g2[uo] * rsqrtf(v2[uo] + EPS);
            cv.x = s;
            cv.y = (b2[uo] - m2[uo]) * s + be2[uo];
            cv.z = w3[uo];
        }
        cs4[tid] = cv;
    }
    __syncthreads();

    const int lane = tid & 63;
    const int wave = tid >> 6;
    const int col  = lane & 15;
    const int quad = lane >> 4;

    short8 bf_[2][3];
#pragma unroll
    for (int j = 0; j < 2; ++j) {
        const int brow = 16 * (2 * wave + j) + col;
#pragma unroll
        for (int s = 0; s < 3; ++s)
            bf_[j][s] = *(const short8*)(&Bs[brow * LDK + 32 * s + 8 * quad]);
    }

    float zp0 = 0.f, zp1 = 0.f;
#pragma unroll
    for (int mt = 0; mt < 7; ++mt) {
        short8 af[3];
#pragma unroll
        for (int s = 0; s < 3; ++s)
            af[s] = *(const short8*)(&As[(16 * mt + col) * LDK + 32 * s + 8 * quad]);

        float4v a0 = {0.f, 0.f, 0.f, 0.f}, a1 = {0.f, 0.f, 0.f, 0.f};
#pragma unroll
        for (int s = 0; s < 3; ++s) {
            a0 = __builtin_amdgcn_mfma_f32_16x16x32_bf16(af[s], bf_[0][s], a0, 0, 0, 0);
            a1 = __builtin_amdgcn_mfma_f32_16x16x32_bf16(af[s], bf_[1][s], a1, 0, 0, 0);
        }
#pragma unroll
        for (int r = 0; r < 4; ++r) {
            const float4 cv = cs4[16 * mt + 4 * quad + r];
            zp0 = fmaf(fmaxf(fmaf(a0[r], cv.x, cv.y), 0.f), cv.z, zp0);
            zp1 = fmaf(fmaxf(fmaf(a1[r], cv.x, cv.y), 0.f), cv.z, zp1);
        }
    }

    zp0 += __shfl_xor(zp0, 16); zp0 += __shfl_xor(zp0, 32);
    zp1 += __shfl_xor(zp1, 16); zp1 += __shfl_xor(zp1, 32);

    if (quad == 0) {
        const float s3 = g3[u] * rsqrtf(v3[u] + EPS);
        const float c3 = (b3[u] - m3[u]) * s3 + be3[u];
        const int bA = b0 + 16 * (2 * wave + 0) + col;
        const int bB = b0 + 16 * (2 * wave + 1) + col;
        zbuf[(size_t)u * BATCH + bA] = fmaxf(fmaf(zp0, s3, c3), 0.f);
        zbuf[(size_t)u * BATCH + bB] = fmaxf(fmaf(zp1, s3, c3), 0.f);
    }
}

// ---------------------------------------------------------------------------
// k_final v2: (byte-identical to R11-R13)
// ---------------------------------------------------------------------------
__global__ __launch_bounds__(256, 4)
void k_final(const float* __restrict__ zbuf, const float* __restrict__ wf,
             const float* __restrict__ bf, float* __restrict__ out)
{
    __shared__ float red[4][64];
    const int nc   = blockIdx.x;
    const int bq   = blockIdx.y;
    const int lane = threadIdx.x & 63;
    const int wave = threadIdx.x >> 6;
    const int b    = bq * 64 + lane;

    float a0 = 0.f, a1 = 0.f, a2 = 0.f;
    const int u0 = wave * 75;
#pragma unroll 5
    for (int i = 0; i < 75; i += 3) {
        a0 = fmaf(zbuf[(size_t)(u0 + i + 0) * BATCH + b], wf[nc * NU + u0 + i + 0], a0);
        a1 = fmaf(zbuf[(size_t)(u0 + i + 1) * BATCH + b], wf[nc * NU + u0 + i + 1], a1);
        a2 = fmaf(zbuf[(size_t)(u0 + i + 2) * BATCH + b], wf[nc * NU + u0 + i + 2], a2);
    }
    red[wave][lane] = (a0 + a1) + a2;
    __syncthreads();
    if (threadIdx.x < 64) {
        const float s = (red[0][lane] + red[1][lane]) + (red[2][lane] + red[3][lane]);
        out[(size_t)b * NCLS + nc] = s + bf[nc];
    }
}

extern "C" void kernel_launch(void* const* d_in, const int* in_sizes, int n_in,
                              void* d_out, int out_size, void* d_ws, size_t ws_size,
                              hipStream_t stream)
{
    const float* x   = (const float*)d_in[0];
    const float* w1  = (const float*)d_in[1];
    const float* b1  = (const float*)d_in[2];
    const float* g1  = (const float*)d_in[3];
    const float* be1 = (const float*)d_in[4];
    const float* m1  = (const float*)d_in[5];
    const float* v1  = (const float*)d_in[6];
    const float* w2  = (const float*)d_in[7];
    const float* b2  = (const float*)d_in[8];
    const float* g2  = (const float*)d_in[9];
    const float* be2 = (const float*)d_in[10];
    const float* m2  = (const float*)d_in[11];
    const float* v2  = (const float*)d_in[12];
    const float* w3  = (const float*)d_in[13];
    const float* b3  = (const float*)d_in[14];
    const float* g3  = (const float*)d_in[15];
    const float* be3 = (const float*)d_in[16];
    const float* m3  = (const float*)d_in[17];
    const float* v3  = (const float*)d_in[18];
    const float* wf  = (const float*)d_in[19];
    const float* bf  = (const float*)d_in[20];

    // workspace layout (bytes):
    //   ypool  bf16 [300][256][96]  @ 0          (14,745,600)
    //   zbuf   f32  [300][256]      @ 14,745,600 (307,200)
    //   Wbh    bf16 [320][104]      @ 15,052,800 (66,560)
    //   Wbl    bf16 [320][104]      @ 15,119,360 (66,560)
    //   xc     u32  [256][4][608]   @ 15,185,920 (2,490,368)
    //   s1c1   f32x2 [304]          @ 17,676,288 (2,432)
    unsigned short* ypool = (unsigned short*)d_ws;
    float* zbuf = (float*)((char*)d_ws + 14745600);
    unsigned short* Wbh = (unsigned short*)((char*)d_ws + 15052800);
    unsigned short* Wbl = (unsigned short*)((char*)d_ws + 15119360);
    unsigned int*   xc  = (unsigned int*)((char*)d_ws + 15185920);
    float2*         sc1 = (float2*)((char*)d_ws + 17676288);

    const int prep_elems = WBROWS * WROW + BATCH * 4 * LIN + MTN * 16;
    k_prep<<<(prep_elems + 255) / 256, 256, 0, stream>>>(
        w1, x, b1, g1, be1, m1, v1, Wbh, Wbl, xc, sc1);

    dim3 gc(BATCH, 6);
    k_conv7<<<gc, 256, 0, stream>>>(Wbh, Wbl, xc, sc1, ypool);

    dim3 gm(NU, BATCH / BH);
    k_mlp<<<gm, 256, 0, stream>>>(ypool, w2, b2, g2, be2, m2, v2,
                                  w3, b3, g3, be3, m3, v3, zbuf);

    dim3 gf(NCLS, 4);
    k_final<<<gf, 256, 0, stream>>>(zbuf, wf, bf, (float*)d_out);
}

// Round 15
// 179.044 us; speedup vs baseline: 1.3516x; 1.3516x over previous
//
#include <hip/hip_runtime.h>
#include <hip/hip_bf16.h>

#define BATCH    256
#define NU       300
#define LIN      608
#define FILT     19
#define LPOOL    84
#define POOL     7
#define HID      100
#define NCLS     50
#define EPS      1e-5f
#define KP       96    // stage-2 K padded (84 -> 96)
#define NP       112   // stage-2 N padded (100 -> 112)
#define LDK      104   // LDS row stride (shorts) for MFMA tiles
#define WROW     104   // packed-W row stride (shorts)
#define WBROWS   320   // packed-W rows (300 + pad)
#define TCHUNK   112   // t per conv block = lcm(16,7)
#define MTN      19    // conv u-tiles (rows 0..303 cover u<300)
#define BH       128   // batches per k_mlp block

typedef __attribute__((ext_vector_type(8))) short short8;   // 8 bf16
typedef __attribute__((ext_vector_type(4))) float float4v;  // MFMA acc

__device__ __forceinline__ unsigned short f2bf(float f) {
    unsigned u = __float_as_uint(f);
    u += 0x7fffu + ((u >> 16) & 1u);       // round-to-nearest-even
    return (unsigned short)(u >> 16);
}
__device__ __forceinline__ float bf2f(unsigned short h) {
    return __uint_as_float(((unsigned)h) << 16);
}

// ---------------------------------------------------------------------------
// k_prep: (byte-identical to R13/R14 — verified)
// ---------------------------------------------------------------------------
__global__ void k_prep(const float* __restrict__ w1, const float* __restrict__ x,
                       const float* __restrict__ b1, const float* __restrict__ g1,
                       const float* __restrict__ be1, const float* __restrict__ m1,
                       const float* __restrict__ v1,
                       unsigned short* __restrict__ Wbh,
                       unsigned short* __restrict__ Wbl,
                       unsigned int* __restrict__ xc,
                       float2* __restrict__ s1c1)
{
    const int idx = blockIdx.x * 256 + threadIdx.x;
    const int NW = WBROWS * WROW;               // 33280
    if (idx < NW) {
        const int u = idx / WROW, kk = idx - u * WROW;
        float wv = 0.f;
        if (u < NU && kk < 96) {
            const int c = kk / 24, tap = kk - 24 * c;
            if (tap < FILT) wv = w1[(u * 4 + c) * FILT + tap];
        }
        const unsigned short hi = f2bf(wv);
        Wbh[idx] = hi;
        Wbl[idx] = f2bf(wv - bf2f(hi));
    }
    const int j = idx - NW;
    if (j >= 0 && j < BATCH * 4 * LIN) {
        const float xv = x[j];
        const unsigned short hi = f2bf(xv);
        const unsigned short lo = f2bf(xv - bf2f(hi));
        xc[j] = (unsigned)hi | ((unsigned)lo << 16);
    }
    const int j2 = j - BATCH * 4 * LIN;
    if (j2 >= 0 && j2 < MTN * 16) {
        float2 v = {0.f, 0.f};
        if (j2 < NU) {
            const float s = g1[j2] * rsqrtf(v1[j2] + EPS);
            v.x = s;
            v.y = (b1[j2] - m1[j2]) * s + be1[j2];
        }
        s1c1[j2] = v;
    }
}

// ---------------------------------------------------------------------------
// k_conv7b: conv(4->300,k=19)+bias+BN+exp+maxpool(7), bf16 MFMA implicit GEMM.
//   2-pass numerics acc = (Wh + Wl)*xh  (validated R14: absmax 0.125).
//   Only Bh staged -> LDS 30.7 KB. launch_bounds (256,4): VGPR cap 128
//   (R14's (256,5) cap=102 spilled the accumulators -> 300 MB HBM scratch
//   traffic, 2.4x regression). 4 blocks/CU, 16 waves.
// ---------------------------------------------------------------------------
__global__ __launch_bounds__(256, 4)
void k_conv7b(const unsigned short* __restrict__ Wbh,
              const unsigned short* __restrict__ Wbl,
              const unsigned int* __restrict__ xc,
              const float2* __restrict__ s1c1,
              unsigned short* __restrict__ ypool)
{
    __shared__ __align__(16) unsigned short Bh[TCHUNK * LDK];  // 23296 B
    __shared__ __align__(16) float Cs[4][TCHUNK * 4];          // 7168 B (per-wave)

    const int tid = threadIdx.x;
    const int b   = blockIdx.x;
    const int tc  = blockIdx.y;
    const int t0  = TCHUNK * tc;
    const int NT  = (tc == 5) ? 2 : 7;         // N-tiles (t) in this block

    // ---- stage B tile (im2col, hi only): row trow, kk = 24c + 8*third + j ----
    for (int i = tid; i < TCHUNK * 12; i += 256) {
        const int trow = i / 12;
        if (trow >= 16 * NT) continue;         // unused rows (tc==5)
        const int rem   = i - 12 * trow;
        const int c     = rem / 3;
        const int third = rem - 3 * c;
        const int kkb   = 24 * c + 8 * third;
        const int tt0   = t0 + trow + 8 * third;
        const unsigned int* src = xc + ((b * 4 + c) * LIN + tt0);

        unsigned int w[8];
        if (third < 2 && tt0 + 8 <= LIN) {     // all 8 taps valid & in range
            const uint4 v0 = *(const uint4*)(src);
            const uint4 v1 = *(const uint4*)(src + 4);
            w[0] = v0.x; w[1] = v0.y; w[2] = v0.z; w[3] = v0.w;
            w[4] = v1.x; w[5] = v1.y; w[6] = v1.z; w[7] = v1.w;
        } else {
#pragma unroll
            for (int j = 0; j < 8; ++j) {
                const int tap = 8 * third + j;
                const int tt  = tt0 + j;
                unsigned int v = 0;
                if (tap < FILT && tt < LIN) v = src[j];
                w[j] = v;
            }
        }
        short8 hv;
#pragma unroll
        for (int j = 0; j < 8; ++j) hv[j] = (short)(w[j] & 0xffffu);
        *(short8*)(&Bh[trow * LDK + kkb]) = hv;
    }
    __syncthreads();   // the ONLY block-wide barrier

    const int lane = tid & 63;
    const int n    = lane & 15;
    const int quad = lane >> 4;
    const int wave = tid >> 6;
    float* Csw = Cs[wave];          // wave-private transposed scratch [112][4]

    const int ep_ul = lane & 3;     // epilogue: u-row within quarter
    const int ep_p  = lane >> 2;    // epilogue: pool window 0..15

    // pair-units k: tiles (2k, 2k+1); k = wave, wave+4, wave+8 (k<10)
    for (int k = wave; k < 10; k += 4) {
        const int mt0 = 2 * k;
        const bool two = (mt0 + 1 < MTN);

        // ---- W fragments (hi & lo) for both tiles, from global (L2-hot) ----
        short8 a0h[3], a0l[3], a1h[3], a1l[3];
        {
            const unsigned short* wrh = Wbh + (size_t)(mt0 * 16 + n) * WROW;
            const unsigned short* wrl = Wbl + (size_t)(mt0 * 16 + n) * WROW;
#pragma unroll
            for (int s = 0; s < 3; ++s) {
                a0h[s] = *(const short8*)(wrh + 32 * s + 8 * quad);
                a0l[s] = *(const short8*)(wrl + 32 * s + 8 * quad);
            }
            const int m1r = two ? (mt0 + 1) : mt0;
            const unsigned short* wrh1 = Wbh + (size_t)(m1r * 16 + n) * WROW;
            const unsigned short* wrl1 = Wbl + (size_t)(m1r * 16 + n) * WROW;
#pragma unroll
            for (int s = 0; s < 3; ++s) {
                a1h[s] = *(const short8*)(wrh1 + 32 * s + 8 * quad);
                a1l[s] = *(const short8*)(wrl1 + 32 * s + 8 * quad);
            }
        }

        // ---- main loop: xh-frags read once per nt, used by BOTH tiles ----
        float4v acc[2][7];
#pragma unroll
        for (int t2 = 0; t2 < 2; ++t2)
#pragma unroll
            for (int nt = 0; nt < 7; ++nt)
                acc[t2][nt] = (float4v){0.f, 0.f, 0.f, 0.f};

#pragma unroll
        for (int nt = 0; nt < 7; ++nt) {
            if (nt < NT) {
                short8 bhf[3];
#pragma unroll
                for (int s = 0; s < 3; ++s)
                    bhf[s] = *(const short8*)(&Bh[(16 * nt + n) * LDK + 32 * s + 8 * quad]);
#pragma unroll
                for (int s = 0; s < 3; ++s)
                    acc[0][nt] = __builtin_amdgcn_mfma_f32_16x16x32_bf16(
                        a0h[s], bhf[s], acc[0][nt], 0, 0, 0);
#pragma unroll
                for (int s = 0; s < 3; ++s)
                    acc[0][nt] = __builtin_amdgcn_mfma_f32_16x16x32_bf16(
                        a0l[s], bhf[s], acc[0][nt], 0, 0, 0);
                if (two) {
#pragma unroll
                    for (int s = 0; s < 3; ++s)
                        acc[1][nt] = __builtin_amdgcn_mfma_f32_16x16x32_bf16(
                            a1h[s], bhf[s], acc[1][nt], 0, 0, 0);
#pragma unroll
                    for (int s = 0; s < 3; ++s)
                        acc[1][nt] = __builtin_amdgcn_mfma_f32_16x16x32_bf16(
                            a1l[s], bhf[s], acc[1][nt], 0, 0, 0);
                }
            }
        }

        // ---- wave-local epilogue per tile, 4 quarters of 4 u-rows ----
#pragma unroll
        for (int t2 = 0; t2 < 2; ++t2) {
            if (t2 == 1 && !two) break;
            const int mt = mt0 + t2;
#pragma unroll
            for (int qq = 0; qq < 4; ++qq) {
                __builtin_amdgcn_fence(__ATOMIC_ACQ_REL, "workgroup");
                if (quad == qq) {
#pragma unroll
                    for (int nt = 0; nt < 7; ++nt) {
                        if (nt < NT)
                            *(float4v*)(&Csw[(16 * nt + n) * 4]) = acc[t2][nt];
                    }
                }
                __builtin_amdgcn_fence(__ATOMIC_ACQ_REL, "workgroup");

                const int uglob = mt * 16 + 4 * qq + ep_ul;
                const int pg    = 16 * tc + ep_p;
                if (uglob < NU) {
                    unsigned short outv = 0;
                    if (pg < LPOOL) {
                        float mx = Csw[(7 * ep_p) * 4 + ep_ul];
#pragma unroll
                        for (int j = 1; j < 7; ++j)
                            mx = fmaxf(mx, Csw[(7 * ep_p + j) * 4 + ep_ul]);
                        const float2 sc = s1c1[uglob];
                        outv = f2bf(__expf(fmaf(mx, sc.x, sc.y)));
                    }
                    if (pg < KP)
                        ypool[((size_t)uglob * BATCH + b) * KP + pg] = outv;
                }
            }
        }
    }
}

// ---------------------------------------------------------------------------
// k_mlp v3: (byte-identical to R9-R14 — verified, pass)
// ---------------------------------------------------------------------------
__global__ __launch_bounds__(256, 3)
void k_mlp(const unsigned short* __restrict__ ypool,
           const float* __restrict__ w2, const float* __restrict__ b2,
           const float* __restrict__ g2, const float* __restrict__ be2,
           const float* __restrict__ m2, const float* __restrict__ v2,
           const float* __restrict__ w3, const float* __restrict__ b3,
           const float* __restrict__ g3, const float* __restrict__ be3,
           const float* __restrict__ m3, const float* __restrict__ v3,
           float* __restrict__ zbuf)
{
    __shared__ __align__(16) unsigned short As[NP * LDK];   // w2 tile 23296 B
    __shared__ __align__(16) unsigned short Bs[BH * LDK];   // y  tile 26624 B
    __shared__ __align__(16) float4 cs4[NP];                // (s2,c2,w3,0)

    const int tid = threadIdx.x;
    const int u   = blockIdx.x;
    const int b0  = blockIdx.y * BH;

    {
        const float* src = w2 + (size_t)u * HID * LPOOL;
        for (int c = tid; c < HID * (LPOOL / 4); c += 256) {
            const int o  = c / (LPOOL / 4);
            const int kc = (c % (LPOOL / 4)) * 4;
            const float4 v = *(const float4*)(src + o * LPOOL + kc);
            unsigned short* d = &As[o * LDK + kc];
            d[0] = f2bf(v.x); d[1] = f2bf(v.y); d[2] = f2bf(v.z); d[3] = f2bf(v.w);
        }
        for (int c = tid; c < HID * 6; c += 256) {            // k-pad [84,96)
            const int o = c / 6, kc = LPOOL + (c % 6) * 2;
            *(unsigned*)(&As[o * LDK + kc]) = 0;
        }
        for (int c = tid; c < (NP - HID) * (KP / 2); c += 256) { // o-pad rows
            const int o = HID + c / (KP / 2), kc = (c % (KP / 2)) * 2;
            *(unsigned*)(&As[o * LDK + kc]) = 0;
        }
    }
    {
        const unsigned short* ys = ypool + ((size_t)u * BATCH + b0) * KP;
        for (int c = tid; c < BH * (KP / 8); c += 256) {
            const int n  = c / (KP / 8);
            const int kc = (c % (KP / 8)) * 8;
            *(short8*)(&Bs[n * LDK + kc]) = *(const short8*)(ys + n * KP + kc);
        }
    }
    if (tid < NP) {
        float4 cv = {0.f, 0.f, 0.f, 0.f};
        if (tid < HID) {
            const int uo = u * HID + tid;
            const float s = g2[uo] * rsqrtf(v2[uo] + EPS);
            cv.x = s;
            cv.y = (b2[uo] - m2[uo]) * s + be2[uo];
            cv.z = w3[uo];
        }
        cs4[tid] = cv;
    }
    __syncthreads();

    const int lane = tid & 63;
    const int wave = tid >> 6;
    const int col  = lane & 15;
    const int quad = lane >> 4;

    short8 bf_[2][3];
#pragma unroll
    for (int j = 0; j < 2; ++j) {
        const int brow = 16 * (2 * wave + j) + col;
#pragma unroll
        for (int s = 0; s < 3; ++s)
            bf_[j][s] = *(const short8*)(&Bs[brow * LDK + 32 * s + 8 * quad]);
    }

    float zp0 = 0.f, zp1 = 0.f;
#pragma unroll
    for (int mt = 0; mt < 7; ++mt) {
        short8 af[3];
#pragma unroll
        for (int s = 0; s < 3; ++s)
            af[s] = *(const short8*)(&As[(16 * mt + col) * LDK + 32 * s + 8 * quad]);

        float4v a0 = {0.f, 0.f, 0.f, 0.f}, a1 = {0.f, 0.f, 0.f, 0.f};
#pragma unroll
        for (int s = 0; s < 3; ++s) {
            a0 = __builtin_amdgcn_mfma_f32_16x16x32_bf16(af[s], bf_[0][s], a0, 0, 0, 0);
            a1 = __builtin_amdgcn_mfma_f32_16x16x32_bf16(af[s], bf_[1][s], a1, 0, 0, 0);
        }
#pragma unroll
        for (int r = 0; r < 4; ++r) {
            const float4 cv = cs4[16 * mt + 4 * quad + r];
            zp0 = fmaf(fmaxf(fmaf(a0[r], cv.x, cv.y), 0.f), cv.z, zp0);
            zp1 = fmaf(fmaxf(fmaf(a1[r], cv.x, cv.y), 0.f), cv.z, zp1);
        }
    }

    zp0 += __shfl_xor(zp0, 16); zp0 += __shfl_xor(zp0, 32);
    zp1 += __shfl_xor(zp1, 16); zp1 += __shfl_xor(zp1, 32);

    if (quad == 0) {
        const float s3 = g3[u] * rsqrtf(v3[u] + EPS);
        const float c3 = (b3[u] - m3[u]) * s3 + be3[u];
        const int bA = b0 + 16 * (2 * wave + 0) + col;
        const int bB = b0 + 16 * (2 * wave + 1) + col;
        zbuf[(size_t)u * BATCH + bA] = fmaxf(fmaf(zp0, s3, c3), 0.f);
        zbuf[(size_t)u * BATCH + bB] = fmaxf(fmaf(zp1, s3, c3), 0.f);
    }
}

// ---------------------------------------------------------------------------
// k_final v2: (byte-identical to R11-R14)
// ---------------------------------------------------------------------------
__global__ __launch_bounds__(256, 4)
void k_final(const float* __restrict__ zbuf, const float* __restrict__ wf,
             const float* __restrict__ bf, float* __restrict__ out)
{
    __shared__ float red[4][64];
    const int nc   = blockIdx.x;
    const int bq   = blockIdx.y;
    const int lane = threadIdx.x & 63;
    const int wave = threadIdx.x >> 6;
    const int b    = bq * 64 + lane;

    float a0 = 0.f, a1 = 0.f, a2 = 0.f;
    const int u0 = wave * 75;
#pragma unroll 5
    for (int i = 0; i < 75; i += 3) {
        a0 = fmaf(zbuf[(size_t)(u0 + i + 0) * BATCH + b], wf[nc * NU + u0 + i + 0], a0);
        a1 = fmaf(zbuf[(size_t)(u0 + i + 1) * BATCH + b], wf[nc * NU + u0 + i + 1], a1);
        a2 = fmaf(zbuf[(size_t)(u0 + i + 2) * BATCH + b], wf[nc * NU + u0 + i + 2], a2);
    }
    red[wave][lane] = (a0 + a1) + a2;
    __syncthreads();
    if (threadIdx.x < 64) {
        const float s = (red[0][lane] + red[1][lane]) + (red[2][lane] + red[3][lane]);
        out[(size_t)b * NCLS + nc] = s + bf[nc];
    }
}

extern "C" void kernel_launch(void* const* d_in, const int* in_sizes, int n_in,
                              void* d_out, int out_size, void* d_ws, size_t ws_size,
                              hipStream_t stream)
{
    const float* x   = (const float*)d_in[0];
    const float* w1  = (const float*)d_in[1];
    const float* b1  = (const float*)d_in[2];
    const float* g1  = (const float*)d_in[3];
    const float* be1 = (const float*)d_in[4];
    const float* m1  = (const float*)d_in[5];
    const float* v1  = (const float*)d_in[6];
    const float* w2  = (const float*)d_in[7];
    const float* b2  = (const float*)d_in[8];
    const float* g2  = (const float*)d_in[9];
    const float* be2 = (const float*)d_in[10];
    const float* m2  = (const float*)d_in[11];
    const float* v2  = (const float*)d_in[12];
    const float* w3  = (const float*)d_in[13];
    const float* b3  = (const float*)d_in[14];
    const float* g3  = (const float*)d_in[15];
    const float* be3 = (const float*)d_in[16];
    const float* m3  = (const float*)d_in[17];
    const float* v3  = (const float*)d_in[18];
    const float* wf  = (const float*)d_in[19];
    const float* bf  = (const float*)d_in[20];

    // workspace layout (bytes):
    //   ypool  bf16 [300][256][96]  @ 0          (14,745,600)
    //   zbuf   f32  [300][256]      @ 14,745,600 (307,200)
    //   Wbh    bf16 [320][104]      @ 15,052,800 (66,560)
    //   Wbl    bf16 [320][104]      @ 15,119,360 (66,560)
    //   xc     u32  [256][4][608]   @ 15,185,920 (2,490,368)
    //   s1c1   f32x2 [304]          @ 17,676,288 (2,432)
    unsigned short* ypool = (unsigned short*)d_ws;
    float* zbuf = (float*)((char*)d_ws + 14745600);
    unsigned short* Wbh = (unsigned short*)((char*)d_ws + 15052800);
    unsigned short* Wbl = (unsigned short*)((char*)d_ws + 15119360);
    unsigned int*   xc  = (unsigned int*)((char*)d_ws + 15185920);
    float2*         sc1 = (float2*)((char*)d_ws + 17676288);

    const int prep_elems = WBROWS * WROW + BATCH * 4 * LIN + MTN * 16;
    k_prep<<<(prep_elems + 255) / 256, 256, 0, stream>>>(
        w1, x, b1, g1, be1, m1, v1, Wbh, Wbl, xc, sc1);

    dim3 gc(BATCH, 6);
    k_conv7b<<<gc, 256, 0, stream>>>(Wbh, Wbl, xc, sc1, ypool);

    dim3 gm(NU, BATCH / BH);
    k_mlp<<<gm, 256, 0, stream>>>(ypool, w2, b2, g2, be2, m2, v2,
                                  w3, b3, g3, be3, m3, v3, zbuf);

    dim3 gf(NCLS, 4);
    k_final<<<gf, 256, 0, stream>>>(zbuf, wf, bf, (float*)d_out);
}

// Round 16
// 159.844 us; speedup vs baseline: 1.5139x; 1.1201x over previous
//
#include <hip/hip_runtime.h>
#include <hip/hip_bf16.h>

#define BATCH    256
#define NU       300
#define LIN      608
#define FILT     19
#define LPOOL    84
#define POOL     7
#define HID      100
#define NCLS     50
#define EPS      1e-5f
#define KP       96    // stage-2 K padded (84 -> 96)
#define NP       112   // stage-2 N padded (100 -> 112)
#define LDK      104   // LDS row stride (shorts) for MFMA tiles
#define WROW     104   // packed-W row stride (shorts)
#define WBROWS   320   // packed-W rows (300 + pad)
#define TCHUNK   112   // t per conv block = lcm(16,7)
#define MTN      19    // conv u-tiles (rows 0..303 cover u<300)
#define BH       128   // batches per k_mlp block

typedef __attribute__((ext_vector_type(8))) short short8;   // 8 bf16
typedef __attribute__((ext_vector_type(4))) float float4v;  // MFMA acc

__device__ __forceinline__ unsigned short f2bf(float f) {
    unsigned u = __float_as_uint(f);
    u += 0x7fffu + ((u >> 16) & 1u);       // round-to-nearest-even
    return (unsigned short)(u >> 16);
}
__device__ __forceinline__ float bf2f(unsigned short h) {
    return __uint_as_float(((unsigned)h) << 16);
}

// ---------------------------------------------------------------------------
// k_prep: (byte-identical to R13-R15 — verified)
// ---------------------------------------------------------------------------
__global__ void k_prep(const float* __restrict__ w1, const float* __restrict__ x,
                       const float* __restrict__ b1, const float* __restrict__ g1,
                       const float* __restrict__ be1, const float* __restrict__ m1,
                       const float* __restrict__ v1,
                       unsigned short* __restrict__ Wbh,
                       unsigned short* __restrict__ Wbl,
                       unsigned int* __restrict__ xc,
                       float2* __restrict__ s1c1)
{
    const int idx = blockIdx.x * 256 + threadIdx.x;
    const int NW = WBROWS * WROW;               // 33280
    if (idx < NW) {
        const int u = idx / WROW, kk = idx - u * WROW;
        float wv = 0.f;
        if (u < NU && kk < 96) {
            const int c = kk / 24, tap = kk - 24 * c;
            if (tap < FILT) wv = w1[(u * 4 + c) * FILT + tap];
        }
        const unsigned short hi = f2bf(wv);
        Wbh[idx] = hi;
        Wbl[idx] = f2bf(wv - bf2f(hi));
    }
    const int j = idx - NW;
    if (j >= 0 && j < BATCH * 4 * LIN) {
        const float xv = x[j];
        const unsigned short hi = f2bf(xv);
        const unsigned short lo = f2bf(xv - bf2f(hi));
        xc[j] = (unsigned)hi | ((unsigned)lo << 16);
    }
    const int j2 = j - BATCH * 4 * LIN;
    if (j2 >= 0 && j2 < MTN * 16) {
        float2 v = {0.f, 0.f};
        if (j2 < NU) {
            const float s = g1[j2] * rsqrtf(v1[j2] + EPS);
            v.x = s;
            v.y = (b1[j2] - m1[j2]) * s + be1[j2];
        }
        s1c1[j2] = v;
    }
}

// ---------------------------------------------------------------------------
// k_conv7c: conv(4->300,k=19)+bias+BN+exp+maxpool(7), bf16 MFMA implicit GEMM.
//   2-pass numerics acc = (Wh + Wl)*xh  (validated R14: absmax 0.125).
//   Only Bh staged -> LDS 30.7 KB.
//   launch_bounds (256,3): VGPR cap 170 — the acc[2][7]+12-W-frag structure
//   needs >128 total regs (R14 cap=102 and R15 cap=128 both spilled to
//   scratch: 300/76 MB HBM write traffic). (256,3) matched conv6's
//   spill-free allocation (VGPR 84). 3 blocks/CU.
// ---------------------------------------------------------------------------
__global__ __launch_bounds__(256, 3)
void k_conv7c(const unsigned short* __restrict__ Wbh,
              const unsigned short* __restrict__ Wbl,
              const unsigned int* __restrict__ xc,
              const float2* __restrict__ s1c1,
              unsigned short* __restrict__ ypool)
{
    __shared__ __align__(16) unsigned short Bh[TCHUNK * LDK];  // 23296 B
    __shared__ __align__(16) float Cs[4][TCHUNK * 4];          // 7168 B (per-wave)

    const int tid = threadIdx.x;
    const int b   = blockIdx.x;
    const int tc  = blockIdx.y;
    const int t0  = TCHUNK * tc;
    const int NT  = (tc == 5) ? 2 : 7;         // N-tiles (t) in this block

    // ---- stage B tile (im2col, hi only): row trow, kk = 24c + 8*third + j ----
    for (int i = tid; i < TCHUNK * 12; i += 256) {
        const int trow = i / 12;
        if (trow >= 16 * NT) continue;         // unused rows (tc==5)
        const int rem   = i - 12 * trow;
        const int c     = rem / 3;
        const int third = rem - 3 * c;
        const int kkb   = 24 * c + 8 * third;
        const int tt0   = t0 + trow + 8 * third;
        const unsigned int* src = xc + ((b * 4 + c) * LIN + tt0);

        unsigned int w[8];
        if (third < 2 && tt0 + 8 <= LIN) {     // all 8 taps valid & in range
            const uint4 v0 = *(const uint4*)(src);
            const uint4 v1 = *(const uint4*)(src + 4);
            w[0] = v0.x; w[1] = v0.y; w[2] = v0.z; w[3] = v0.w;
            w[4] = v1.x; w[5] = v1.y; w[6] = v1.z; w[7] = v1.w;
        } else {
#pragma unroll
            for (int j = 0; j < 8; ++j) {
                const int tap = 8 * third + j;
                const int tt  = tt0 + j;
                unsigned int v = 0;
                if (tap < FILT && tt < LIN) v = src[j];
                w[j] = v;
            }
        }
        short8 hv;
#pragma unroll
        for (int j = 0; j < 8; ++j) hv[j] = (short)(w[j] & 0xffffu);
        *(short8*)(&Bh[trow * LDK + kkb]) = hv;
    }
    __syncthreads();   // the ONLY block-wide barrier

    const int lane = tid & 63;
    const int n    = lane & 15;
    const int quad = lane >> 4;
    const int wave = tid >> 6;
    float* Csw = Cs[wave];          // wave-private transposed scratch [112][4]

    const int ep_ul = lane & 3;     // epilogue: u-row within quarter
    const int ep_p  = lane >> 2;    // epilogue: pool window 0..15

    // pair-units k: tiles (2k, 2k+1); k = wave, wave+4, wave+8 (k<10)
    for (int k = wave; k < 10; k += 4) {
        const int mt0 = 2 * k;
        const bool two = (mt0 + 1 < MTN);

        // ---- W fragments (hi & lo) for both tiles, from global (L2-hot) ----
        short8 a0h[3], a0l[3], a1h[3], a1l[3];
        {
            const unsigned short* wrh = Wbh + (size_t)(mt0 * 16 + n) * WROW;
            const unsigned short* wrl = Wbl + (size_t)(mt0 * 16 + n) * WROW;
#pragma unroll
            for (int s = 0; s < 3; ++s) {
                a0h[s] = *(const short8*)(wrh + 32 * s + 8 * quad);
                a0l[s] = *(const short8*)(wrl + 32 * s + 8 * quad);
            }
            const int m1r = two ? (mt0 + 1) : mt0;
            const unsigned short* wrh1 = Wbh + (size_t)(m1r * 16 + n) * WROW;
            const unsigned short* wrl1 = Wbl + (size_t)(m1r * 16 + n) * WROW;
#pragma unroll
            for (int s = 0; s < 3; ++s) {
                a1h[s] = *(const short8*)(wrh1 + 32 * s + 8 * quad);
                a1l[s] = *(const short8*)(wrl1 + 32 * s + 8 * quad);
            }
        }

        // ---- main loop: xh-frags read once per nt, used by BOTH tiles ----
        float4v acc[2][7];
#pragma unroll
        for (int t2 = 0; t2 < 2; ++t2)
#pragma unroll
            for (int nt = 0; nt < 7; ++nt)
                acc[t2][nt] = (float4v){0.f, 0.f, 0.f, 0.f};

#pragma unroll
        for (int nt = 0; nt < 7; ++nt) {
            if (nt < NT) {
                short8 bhf[3];
#pragma unroll
                for (int s = 0; s < 3; ++s)
                    bhf[s] = *(const short8*)(&Bh[(16 * nt + n) * LDK + 32 * s + 8 * quad]);
#pragma unroll
                for (int s = 0; s < 3; ++s)
                    acc[0][nt] = __builtin_amdgcn_mfma_f32_16x16x32_bf16(
                        a0h[s], bhf[s], acc[0][nt], 0, 0, 0);
#pragma unroll
                for (int s = 0; s < 3; ++s)
                    acc[0][nt] = __builtin_amdgcn_mfma_f32_16x16x32_bf16(
                        a0l[s], bhf[s], acc[0][nt], 0, 0, 0);
                if (two) {
#pragma unroll
                    for (int s = 0; s < 3; ++s)
                        acc[1][nt] = __builtin_amdgcn_mfma_f32_16x16x32_bf16(
                            a1h[s], bhf[s], acc[1][nt], 0, 0, 0);
#pragma unroll
                    for (int s = 0; s < 3; ++s)
                        acc[1][nt] = __builtin_amdgcn_mfma_f32_16x16x32_bf16(
                            a1l[s], bhf[s], acc[1][nt], 0, 0, 0);
                }
            }
        }

        // ---- wave-local epilogue per tile, 4 quarters of 4 u-rows ----
#pragma unroll
        for (int t2 = 0; t2 < 2; ++t2) {
            if (t2 == 1 && !two) break;
            const int mt = mt0 + t2;
#pragma unroll
            for (int qq = 0; qq < 4; ++qq) {
                __builtin_amdgcn_fence(__ATOMIC_ACQ_REL, "workgroup");
                if (quad == qq) {
#pragma unroll
                    for (int nt = 0; nt < 7; ++nt) {
                        if (nt < NT)
                            *(float4v*)(&Csw[(16 * nt + n) * 4]) = acc[t2][nt];
                    }
                }
                __builtin_amdgcn_fence(__ATOMIC_ACQ_REL, "workgroup");

                const int uglob = mt * 16 + 4 * qq + ep_ul;
                const int pg    = 16 * tc + ep_p;
                if (uglob < NU) {
                    unsigned short outv = 0;
                    if (pg < LPOOL) {
                        float mx = Csw[(7 * ep_p) * 4 + ep_ul];
#pragma unroll
                        for (int j = 1; j < 7; ++j)
                            mx = fmaxf(mx, Csw[(7 * ep_p + j) * 4 + ep_ul]);
                        const float2 sc = s1c1[uglob];
                        outv = f2bf(__expf(fmaf(mx, sc.x, sc.y)));
                    }
                    if (pg < KP)
                        ypool[((size_t)uglob * BATCH + b) * KP + pg] = outv;
                }
            }
        }
    }
}

// ---------------------------------------------------------------------------
// k_mlp v3: (byte-identical to R9-R15 — verified, pass)
// ---------------------------------------------------------------------------
__global__ __launch_bounds__(256, 3)
void k_mlp(const unsigned short* __restrict__ ypool,
           const float* __restrict__ w2, const float* __restrict__ b2,
           const float* __restrict__ g2, const float* __restrict__ be2,
           const float* __restrict__ m2, const float* __restrict__ v2,
           const float* __restrict__ w3, const float* __restrict__ b3,
           const float* __restrict__ g3, const float* __restrict__ be3,
           const float* __restrict__ m3, const float* __restrict__ v3,
           float* __restrict__ zbuf)
{
    __shared__ __align__(16) unsigned short As[NP * LDK];   // w2 tile 23296 B
    __shared__ __align__(16) unsigned short Bs[BH * LDK];   // y  tile 26624 B
    __shared__ __align__(16) float4 cs4[NP];                // (s2,c2,w3,0)

    const int tid = threadIdx.x;
    const int u   = blockIdx.x;
    const int b0  = blockIdx.y * BH;

    {
        const float* src = w2 + (size_t)u * HID * LPOOL;
        for (int c = tid; c < HID * (LPOOL / 4); c += 256) {
            const int o  = c / (LPOOL / 4);
            const int kc = (c % (LPOOL / 4)) * 4;
            const float4 v = *(const float4*)(src + o * LPOOL + kc);
            unsigned short* d = &As[o * LDK + kc];
            d[0] = f2bf(v.x); d[1] = f2bf(v.y); d[2] = f2bf(v.z); d[3] = f2bf(v.w);
        }
        for (int c = tid; c < HID * 6; c += 256) {            // k-pad [84,96)
            const int o = c / 6, kc = LPOOL + (c % 6) * 2;
            *(unsigned*)(&As[o * LDK + kc]) = 0;
        }
        for (int c = tid; c < (NP - HID) * (KP / 2); c += 256) { // o-pad rows
            const int o = HID + c / (KP / 2), kc = (c % (KP / 2)) * 2;
            *(unsigned*)(&As[o * LDK + kc]) = 0;
        }
    }
    {
        const unsigned short* ys = ypool + ((size_t)u * BATCH + b0) * KP;
        for (int c = tid; c < BH * (KP / 8); c += 256) {
            const int n  = c / (KP / 8);
            const int kc = (c % (KP / 8)) * 8;
            *(short8*)(&Bs[n * LDK + kc]) = *(const short8*)(ys + n * KP + kc);
        }
    }
    if (tid < NP) {
        float4 cv = {0.f, 0.f, 0.f, 0.f};
        if (tid < HID) {
            const int uo = u * HID + tid;
            const float s = g2[uo] * rsqrtf(v2[uo] + EPS);
            cv.x = s;
            cv.y = (b2[uo] - m2[uo]) * s + be2[uo];
            cv.z = w3[uo];
        }
        cs4[tid] = cv;
    }
    __syncthreads();

    const int lane = tid & 63;
    const int wave = tid >> 6;
    const int col  = lane & 15;
    const int quad = lane >> 4;

    short8 bf_[2][3];
#pragma unroll
    for (int j = 0; j < 2; ++j) {
        const int brow = 16 * (2 * wave + j) + col;
#pragma unroll
        for (int s = 0; s < 3; ++s)
            bf_[j][s] = *(const short8*)(&Bs[brow * LDK + 32 * s + 8 * quad]);
    }

    float zp0 = 0.f, zp1 = 0.f;
#pragma unroll
    for (int mt = 0; mt < 7; ++mt) {
        short8 af[3];
#pragma unroll
        for (int s = 0; s < 3; ++s)
            af[s] = *(const short8*)(&As[(16 * mt + col) * LDK + 32 * s + 8 * quad]);

        float4v a0 = {0.f, 0.f, 0.f, 0.f}, a1 = {0.f, 0.f, 0.f, 0.f};
#pragma unroll
        for (int s = 0; s < 3; ++s) {
            a0 = __builtin_amdgcn_mfma_f32_16x16x32_bf16(af[s], bf_[0][s], a0, 0, 0, 0);
            a1 = __builtin_amdgcn_mfma_f32_16x16x32_bf16(af[s], bf_[1][s], a1, 0, 0, 0);
        }
#pragma unroll
        for (int r = 0; r < 4; ++r) {
            const float4 cv = cs4[16 * mt + 4 * quad + r];
            zp0 = fmaf(fmaxf(fmaf(a0[r], cv.x, cv.y), 0.f), cv.z, zp0);
            zp1 = fmaf(fmaxf(fmaf(a1[r], cv.x, cv.y), 0.f), cv.z, zp1);
        }
    }

    zp0 += __shfl_xor(zp0, 16); zp0 += __shfl_xor(zp0, 32);
    zp1 += __shfl_xor(zp1, 16); zp1 += __shfl_xor(zp1, 32);

    if (quad == 0) {
        const float s3 = g3[u] * rsqrtf(v3[u] + EPS);
        const float c3 = (b3[u] - m3[u]) * s3 + be3[u];
        const int bA = b0 + 16 * (2 * wave + 0) + col;
        const int bB = b0 + 16 * (2 * wave + 1) + col;
        zbuf[(size_t)u * BATCH + bA] = fmaxf(fmaf(zp0, s3, c3), 0.f);
        zbuf[(size_t)u * BATCH + bB] = fmaxf(fmaf(zp1, s3, c3), 0.f);
    }
}

// ---------------------------------------------------------------------------
// k_final v2: (byte-identical to R11-R15)
// ---------------------------------------------------------------------------
__global__ __launch_bounds__(256, 4)
void k_final(const float* __restrict__ zbuf, const float* __restrict__ wf,
             const float* __restrict__ bf, float* __restrict__ out)
{
    __shared__ float red[4][64];
    const int nc   = blockIdx.x;
    const int bq   = blockIdx.y;
    const int lane = threadIdx.x & 63;
    const int wave = threadIdx.x >> 6;
    const int b    = bq * 64 + lane;

    float a0 = 0.f, a1 = 0.f, a2 = 0.f;
    const int u0 = wave * 75;
#pragma unroll 5
    for (int i = 0; i < 75; i += 3) {
        a0 = fmaf(zbuf[(size_t)(u0 + i + 0) * BATCH + b], wf[nc * NU + u0 + i + 0], a0);
        a1 = fmaf(zbuf[(size_t)(u0 + i + 1) * BATCH + b], wf[nc * NU + u0 + i + 1], a1);
        a2 = fmaf(zbuf[(size_t)(u0 + i + 2) * BATCH + b], wf[nc * NU + u0 + i + 2], a2);
    }
    red[wave][lane] = (a0 + a1) + a2;
    __syncthreads();
    if (threadIdx.x < 64) {
        const float s = (red[0][lane] + red[1][lane]) + (red[2][lane] + red[3][lane]);
        out[(size_t)b * NCLS + nc] = s + bf[nc];
    }
}

extern "C" void kernel_launch(void* const* d_in, const int* in_sizes, int n_in,
                              void* d_out, int out_size, void* d_ws, size_t ws_size,
                              hipStream_t stream)
{
    const float* x   = (const float*)d_in[0];
    const float* w1  = (const float*)d_in[1];
    const float* b1  = (const float*)d_in[2];
    const float* g1  = (const float*)d_in[3];
    const float* be1 = (const float*)d_in[4];
    const float* m1  = (const float*)d_in[5];
    const float* v1  = (const float*)d_in[6];
    const float* w2  = (const float*)d_in[7];
    const float* b2  = (const float*)d_in[8];
    const float* g2  = (const float*)d_in[9];
    const float* be2 = (const float*)d_in[10];
    const float* m2  = (const float*)d_in[11];
    const float* v2  = (const float*)d_in[12];
    const float* w3  = (const float*)d_in[13];
    const float* b3  = (const float*)d_in[14];
    const float* g3  = (const float*)d_in[15];
    const float* be3 = (const float*)d_in[16];
    const float* m3  = (const float*)d_in[17];
    const float* v3  = (const float*)d_in[18];
    const float* wf  = (const float*)d_in[19];
    const float* bf  = (const float*)d_in[20];

    // workspace layout (bytes):
    //   ypool  bf16 [300][256][96]  @ 0          (14,745,600)
    //   zbuf   f32  [300][256]      @ 14,745,600 (307,200)
    //   Wbh    bf16 [320][104]      @ 15,052,800 (66,560)
    //   Wbl    bf16 [320][104]      @ 15,119,360 (66,560)
    //   xc     u32  [256][4][608]   @ 15,185,920 (2,490,368)
    //   s1c1   f32x2 [304]          @ 17,676,288 (2,432)
    unsigned short* ypool = (unsigned short*)d_ws;
    float* zbuf = (float*)((char*)d_ws + 14745600);
    unsigned short* Wbh = (unsigned short*)((char*)d_ws + 15052800);
    unsigned short* Wbl = (unsigned short*)((char*)d_ws + 15119360);
    unsigned int*   xc  = (unsigned int*)((char*)d_ws + 15185920);
    float2*         sc1 = (float2*)((char*)d_ws + 17676288);

    const int prep_elems = WBROWS * WROW + BATCH * 4 * LIN + MTN * 16;
    k_prep<<<(prep_elems + 255) / 256, 256, 0, stream>>>(
        w1, x, b1, g1, be1, m1, v1, Wbh, Wbl, xc, sc1);

    dim3 gc(BATCH, 6);
    k_conv7c<<<gc, 256, 0, stream>>>(Wbh, Wbl, xc, sc1, ypool);

    dim3 gm(NU, BATCH / BH);
    k_mlp<<<gm, 256, 0, stream>>>(ypool, w2, b2, g2, be2, m2, v2,
                                  w3, b3, g3, be3, m3, v3, zbuf);

    dim3 gf(NCLS, 4);
    k_final<<<gf, 256, 0, stream>>>(zbuf, wf, bf, (float*)d_out);
}

// Round 17
// 159.686 us; speedup vs baseline: 1.5154x; 1.0010x over previous
//
#include <hip/hip_runtime.h>
#include <hip/hip_bf16.h>

#define BATCH    256
#define NU       300
#define LIN      608
#define FILT     19
#define LPOOL    84
#define POOL     7
#define HID      100
#define NCLS     50
#define EPS      1e-5f
#define KP       96    // stage-2 K padded (84 -> 96)
#define NP       112   // stage-2 N padded (100 -> 112)
#define LDK      104   // LDS row stride (shorts) for MFMA tiles
#define WROW     104   // packed-W row stride (shorts)
#define WBROWS   320   // packed-W rows (300 + pad)
#define TCHUNK   112   // t per conv block = lcm(16,7)
#define MTN      19    // conv u-tiles (rows 0..303 cover u<300)
#define BH       128   // batches per k_mlp block

typedef __attribute__((ext_vector_type(8))) short short8;   // 8 bf16
typedef __attribute__((ext_vector_type(4))) float float4v;  // MFMA acc

// same-wave LDS producer->consumer ordering: lgkmcnt(0) ONLY.
// (__builtin_amdgcn_fence(workgroup) lowers to vmcnt(0)+lgkmcnt(0) and was
// draining the scattered ypool stores ~40x per wave — the R16 stall.)
#define LDS_WAIT() __asm__ __volatile__("s_waitcnt lgkmcnt(0)" ::: "memory")

__device__ __forceinline__ unsigned short f2bf(float f) {
    unsigned u = __float_as_uint(f);
    u += 0x7fffu + ((u >> 16) & 1u);       // round-to-nearest-even
    return (unsigned short)(u >> 16);
}
__device__ __forceinline__ float bf2f(unsigned short h) {
    return __uint_as_float(((unsigned)h) << 16);
}

// ---------------------------------------------------------------------------
// k_prep: (byte-identical to R13-R16 — verified)
// ---------------------------------------------------------------------------
__global__ void k_prep(const float* __restrict__ w1, const float* __restrict__ x,
                       const float* __restrict__ b1, const float* __restrict__ g1,
                       const float* __restrict__ be1, const float* __restrict__ m1,
                       const float* __restrict__ v1,
                       unsigned short* __restrict__ Wbh,
                       unsigned short* __restrict__ Wbl,
                       unsigned int* __restrict__ xc,
                       float2* __restrict__ s1c1)
{
    const int idx = blockIdx.x * 256 + threadIdx.x;
    const int NW = WBROWS * WROW;               // 33280
    if (idx < NW) {
        const int u = idx / WROW, kk = idx - u * WROW;
        float wv = 0.f;
        if (u < NU && kk < 96) {
            const int c = kk / 24, tap = kk - 24 * c;
            if (tap < FILT) wv = w1[(u * 4 + c) * FILT + tap];
        }
        const unsigned short hi = f2bf(wv);
        Wbh[idx] = hi;
        Wbl[idx] = f2bf(wv - bf2f(hi));
    }
    const int j = idx - NW;
    if (j >= 0 && j < BATCH * 4 * LIN) {
        const float xv = x[j];
        const unsigned short hi = f2bf(xv);
        const unsigned short lo = f2bf(xv - bf2f(hi));
        xc[j] = (unsigned)hi | ((unsigned)lo << 16);
    }
    const int j2 = j - BATCH * 4 * LIN;
    if (j2 >= 0 && j2 < MTN * 16) {
        float2 v = {0.f, 0.f};
        if (j2 < NU) {
            const float s = g1[j2] * rsqrtf(v1[j2] + EPS);
            v.x = s;
            v.y = (b1[j2] - m1[j2]) * s + be1[j2];
        }
        s1c1[j2] = v;
    }
}

// ---------------------------------------------------------------------------
// k_conv7d: conv(4->300,k=19)+bias+BN+exp+maxpool(7), bf16 MFMA implicit GEMM.
//   2-pass numerics acc = (Wh + Wl)*xh  (validated: absmax 0.125).
//   vs R16 (single change): the two workgroup acq_rel fences per epilogue
//   quarter are replaced with lgkm-only waitcnts (LDS_WAIT). The Cs scratch
//   is wave-private, so only same-wave LDS ordering is required — the fence's
//   implicit vmcnt(0) was draining ypool stores ~40x per wave.
// ---------------------------------------------------------------------------
__global__ __launch_bounds__(256, 3)
void k_conv7d(const unsigned short* __restrict__ Wbh,
              const unsigned short* __restrict__ Wbl,
              const unsigned int* __restrict__ xc,
              const float2* __restrict__ s1c1,
              unsigned short* __restrict__ ypool)
{
    __shared__ __align__(16) unsigned short Bh[TCHUNK * LDK];  // 23296 B
    __shared__ __align__(16) float Cs[4][TCHUNK * 4];          // 7168 B (per-wave)

    const int tid = threadIdx.x;
    const int b   = blockIdx.x;
    const int tc  = blockIdx.y;
    const int t0  = TCHUNK * tc;
    const int NT  = (tc == 5) ? 2 : 7;         // N-tiles (t) in this block

    // ---- stage B tile (im2col, hi only): row trow, kk = 24c + 8*third + j ----
    for (int i = tid; i < TCHUNK * 12; i += 256) {
        const int trow = i / 12;
        if (trow >= 16 * NT) continue;         // unused rows (tc==5)
        const int rem   = i - 12 * trow;
        const int c     = rem / 3;
        const int third = rem - 3 * c;
        const int kkb   = 24 * c + 8 * third;
        const int tt0   = t0 + trow + 8 * third;
        const unsigned int* src = xc + ((b * 4 + c) * LIN + tt0);

        unsigned int w[8];
        if (third < 2 && tt0 + 8 <= LIN) {     // all 8 taps valid & in range
            const uint4 v0 = *(const uint4*)(src);
            const uint4 v1 = *(const uint4*)(src + 4);
            w[0] = v0.x; w[1] = v0.y; w[2] = v0.z; w[3] = v0.w;
            w[4] = v1.x; w[5] = v1.y; w[6] = v1.z; w[7] = v1.w;
        } else {
#pragma unroll
            for (int j = 0; j < 8; ++j) {
                const int tap = 8 * third + j;
                const int tt  = tt0 + j;
                unsigned int v = 0;
                if (tap < FILT && tt < LIN) v = src[j];
                w[j] = v;
            }
        }
        short8 hv;
#pragma unroll
        for (int j = 0; j < 8; ++j) hv[j] = (short)(w[j] & 0xffffu);
        *(short8*)(&Bh[trow * LDK + kkb]) = hv;
    }
    __syncthreads();   // the ONLY block-wide barrier

    const int lane = tid & 63;
    const int n    = lane & 15;
    const int quad = lane >> 4;
    const int wave = tid >> 6;
    float* Csw = Cs[wave];          // wave-private transposed scratch [112][4]

    const int ep_ul = lane & 3;     // epilogue: u-row within quarter
    const int ep_p  = lane >> 2;    // epilogue: pool window 0..15

    // pair-units k: tiles (2k, 2k+1); k = wave, wave+4, wave+8 (k<10)
    for (int k = wave; k < 10; k += 4) {
        const int mt0 = 2 * k;
        const bool two = (mt0 + 1 < MTN);

        // ---- W fragments (hi & lo) for both tiles, from global (L2-hot) ----
        short8 a0h[3], a0l[3], a1h[3], a1l[3];
        {
            const unsigned short* wrh = Wbh + (size_t)(mt0 * 16 + n) * WROW;
            const unsigned short* wrl = Wbl + (size_t)(mt0 * 16 + n) * WROW;
#pragma unroll
            for (int s = 0; s < 3; ++s) {
                a0h[s] = *(const short8*)(wrh + 32 * s + 8 * quad);
                a0l[s] = *(const short8*)(wrl + 32 * s + 8 * quad);
            }
            const int m1r = two ? (mt0 + 1) : mt0;
            const unsigned short* wrh1 = Wbh + (size_t)(m1r * 16 + n) * WROW;
            const unsigned short* wrl1 = Wbl + (size_t)(m1r * 16 + n) * WROW;
#pragma unroll
            for (int s = 0; s < 3; ++s) {
                a1h[s] = *(const short8*)(wrh1 + 32 * s + 8 * quad);
                a1l[s] = *(const short8*)(wrl1 + 32 * s + 8 * quad);
            }
        }

        // ---- main loop: xh-frags read once per nt, used by BOTH tiles ----
        float4v acc[2][7];
#pragma unroll
        for (int t2 = 0; t2 < 2; ++t2)
#pragma unroll
            for (int nt = 0; nt < 7; ++nt)
                acc[t2][nt] = (float4v){0.f, 0.f, 0.f, 0.f};

#pragma unroll
        for (int nt = 0; nt < 7; ++nt) {
            if (nt < NT) {
                short8 bhf[3];
#pragma unroll
                for (int s = 0; s < 3; ++s)
                    bhf[s] = *(const short8*)(&Bh[(16 * nt + n) * LDK + 32 * s + 8 * quad]);
#pragma unroll
                for (int s = 0; s < 3; ++s)
                    acc[0][nt] = __builtin_amdgcn_mfma_f32_16x16x32_bf16(
                        a0h[s], bhf[s], acc[0][nt], 0, 0, 0);
#pragma unroll
                for (int s = 0; s < 3; ++s)
                    acc[0][nt] = __builtin_amdgcn_mfma_f32_16x16x32_bf16(
                        a0l[s], bhf[s], acc[0][nt], 0, 0, 0);
                if (two) {
#pragma unroll
                    for (int s = 0; s < 3; ++s)
                        acc[1][nt] = __builtin_amdgcn_mfma_f32_16x16x32_bf16(
                            a1h[s], bhf[s], acc[1][nt], 0, 0, 0);
#pragma unroll
                    for (int s = 0; s < 3; ++s)
                        acc[1][nt] = __builtin_amdgcn_mfma_f32_16x16x32_bf16(
                            a1l[s], bhf[s], acc[1][nt], 0, 0, 0);
                }
            }
        }

        // ---- wave-local epilogue per tile, 4 quarters of 4 u-rows ----
#pragma unroll
        for (int t2 = 0; t2 < 2; ++t2) {
            if (t2 == 1 && !two) break;
            const int mt = mt0 + t2;
#pragma unroll
            for (int qq = 0; qq < 4; ++qq) {
                LDS_WAIT();   // WAR: previous quarter's pool reads complete
                if (quad == qq) {
#pragma unroll
                    for (int nt = 0; nt < 7; ++nt) {
                        if (nt < NT)
                            *(float4v*)(&Csw[(16 * nt + n) * 4]) = acc[t2][nt];
                    }
                }
                LDS_WAIT();   // RAW: writes visible to all lanes of this wave

                const int uglob = mt * 16 + 4 * qq + ep_ul;
                const int pg    = 16 * tc + ep_p;
                if (uglob < NU) {
                    unsigned short outv = 0;
                    if (pg < LPOOL) {
                        float mx = Csw[(7 * ep_p) * 4 + ep_ul];
#pragma unroll
                        for (int j = 1; j < 7; ++j)
                            mx = fmaxf(mx, Csw[(7 * ep_p + j) * 4 + ep_ul]);
                        const float2 sc = s1c1[uglob];
                        outv = f2bf(__expf(fmaf(mx, sc.x, sc.y)));
                    }
                    if (pg < KP)
                        ypool[((size_t)uglob * BATCH + b) * KP + pg] = outv;
                }
            }
        }
    }
}

// ---------------------------------------------------------------------------
// k_mlp v3: (byte-identical to R9-R16 — verified, pass)
// ---------------------------------------------------------------------------
__global__ __launch_bounds__(256, 3)
void k_mlp(const unsigned short* __restrict__ ypool,
           const float* __restrict__ w2, const float* __restrict__ b2,
           const float* __restrict__ g2, const float* __restrict__ be2,
           const float* __restrict__ m2, const float* __restrict__ v2,
           const float* __restrict__ w3, const float* __restrict__ b3,
           const float* __restrict__ g3, const float* __restrict__ be3,
           const float* __restrict__ m3, const float* __restrict__ v3,
           float* __restrict__ zbuf)
{
    __shared__ __align__(16) unsigned short As[NP * LDK];   // w2 tile 23296 B
    __shared__ __align__(16) unsigned short Bs[BH * LDK];   // y  tile 26624 B
    __shared__ __align__(16) float4 cs4[NP];                // (s2,c2,w3,0)

    const int tid = threadIdx.x;
    const int u   = blockIdx.x;
    const int b0  = blockIdx.y * BH;

    {
        const float* src = w2 + (size_t)u * HID * LPOOL;
        for (int c = tid; c < HID * (LPOOL / 4); c += 256) {
            const int o  = c / (LPOOL / 4);
            const int kc = (c % (LPOOL / 4)) * 4;
            const float4 v = *(const float4*)(src + o * LPOOL + kc);
            unsigned short* d = &As[o * LDK + kc];
            d[0] = f2bf(v.x); d[1] = f2bf(v.y); d[2] = f2bf(v.z); d[3] = f2bf(v.w);
        }
        for (int c = tid; c < HID * 6; c += 256) {            // k-pad [84,96)
            const int o = c / 6, kc = LPOOL + (c % 6) * 2;
            *(unsigned*)(&As[o * LDK + kc]) = 0;
        }
        for (int c = tid; c < (NP - HID) * (KP / 2); c += 256) { // o-pad rows
            const int o = HID + c / (KP / 2), kc = (c % (KP / 2)) * 2;
            *(unsigned*)(&As[o * LDK + kc]) = 0;
        }
    }
    {
        const unsigned short* ys = ypool + ((size_t)u * BATCH + b0) * KP;
        for (int c = tid; c < BH * (KP / 8); c += 256) {
            const int n  = c / (KP / 8);
            const int kc = (c % (KP / 8)) * 8;
            *(short8*)(&Bs[n * LDK + kc]) = *(const short8*)(ys + n * KP + kc);
        }
    }
    if (tid < NP) {
        float4 cv = {0.f, 0.f, 0.f, 0.f};
        if (tid < HID) {
            const int uo = u * HID + tid;
            const float s = g2[uo] * rsqrtf(v2[uo] + EPS);
            cv.x = s;
            cv.y = (b2[uo] - m2[uo]) * s + be2[uo];
            cv.z = w3[uo];
        }
        cs4[tid] = cv;
    }
    __syncthreads();

    const int lane = tid & 63;
    const int wave = tid >> 6;
    const int col  = lane & 15;
    const int quad = lane >> 4;

    short8 bf_[2][3];
#pragma unroll
    for (int j = 0; j < 2; ++j) {
        const int brow = 16 * (2 * wave + j) + col;
#pragma unroll
        for (int s = 0; s < 3; ++s)
            bf_[j][s] = *(const short8*)(&Bs[brow * LDK + 32 * s + 8 * quad]);
    }

    float zp0 = 0.f, zp1 = 0.f;
#pragma unroll
    for (int mt = 0; mt < 7; ++mt) {
        short8 af[3];
#pragma unroll
        for (int s = 0; s < 3; ++s)
            af[s] = *(const short8*)(&As[(16 * mt + col) * LDK + 32 * s + 8 * quad]);

        float4v a0 = {0.f, 0.f, 0.f, 0.f}, a1 = {0.f, 0.f, 0.f, 0.f};
#pragma unroll
        for (int s = 0; s < 3; ++s) {
            a0 = __builtin_amdgcn_mfma_f32_16x16x32_bf16(af[s], bf_[0][s], a0, 0, 0, 0);
            a1 = __builtin_amdgcn_mfma_f32_16x16x32_bf16(af[s], bf_[1][s], a1, 0, 0, 0);
        }
#pragma unroll
        for (int r = 0; r < 4; ++r) {
            const float4 cv = cs4[16 * mt + 4 * quad + r];
            zp0 = fmaf(fmaxf(fmaf(a0[r], cv.x, cv.y), 0.f), cv.z, zp0);
            zp1 = fmaf(fmaxf(fmaf(a1[r], cv.x, cv.y), 0.f), cv.z, zp1);
        }
    }

    zp0 += __shfl_xor(zp0, 16); zp0 += __shfl_xor(zp0, 32);
    zp1 += __shfl_xor(zp1, 16); zp1 += __shfl_xor(zp1, 32);

    if (quad == 0) {
        const float s3 = g3[u] * rsqrtf(v3[u] + EPS);
        const float c3 = (b3[u] - m3[u]) * s3 + be3[u];
        const int bA = b0 + 16 * (2 * wave + 0) + col;
        const int bB = b0 + 16 * (2 * wave + 1) + col;
        zbuf[(size_t)u * BATCH + bA] = fmaxf(fmaf(zp0, s3, c3), 0.f);
        zbuf[(size_t)u * BATCH + bB] = fmaxf(fmaf(zp1, s3, c3), 0.f);
    }
}

// ---------------------------------------------------------------------------
// k_final v2: (byte-identical to R11-R16)
// ---------------------------------------------------------------------------
__global__ __launch_bounds__(256, 4)
void k_final(const float* __restrict__ zbuf, const float* __restrict__ wf,
             const float* __restrict__ bf, float* __restrict__ out)
{
    __shared__ float red[4][64];
    const int nc   = blockIdx.x;
    const int bq   = blockIdx.y;
    const int lane = threadIdx.x & 63;
    const int wave = threadIdx.x >> 6;
    const int b    = bq * 64 + lane;

    float a0 = 0.f, a1 = 0.f, a2 = 0.f;
    const int u0 = wave * 75;
#pragma unroll 5
    for (int i = 0; i < 75; i += 3) {
        a0 = fmaf(zbuf[(size_t)(u0 + i + 0) * BATCH + b], wf[nc * NU + u0 + i + 0], a0);
        a1 = fmaf(zbuf[(size_t)(u0 + i + 1) * BATCH + b], wf[nc * NU + u0 + i + 1], a1);
        a2 = fmaf(zbuf[(size_t)(u0 + i + 2) * BATCH + b], wf[nc * NU + u0 + i + 2], a2);
    }
    red[wave][lane] = (a0 + a1) + a2;
    __syncthreads();
    if (threadIdx.x < 64) {
        const float s = (red[0][lane] + red[1][lane]) + (red[2][lane] + red[3][lane]);
        out[(size_t)b * NCLS + nc] = s + bf[nc];
    }
}

extern "C" void kernel_launch(void* const* d_in, const int* in_sizes, int n_in,
                              void* d_out, int out_size, void* d_ws, size_t ws_size,
                              hipStream_t stream)
{
    const float* x   = (const float*)d_in[0];
    const float* w1  = (const float*)d_in[1];
    const float* b1  = (const float*)d_in[2];
    const float* g1  = (const float*)d_in[3];
    const float* be1 = (const float*)d_in[4];
    const float* m1  = (const float*)d_in[5];
    const float* v1  = (const float*)d_in[6];
    const float* w2  = (const float*)d_in[7];
    const float* b2  = (const float*)d_in[8];
    const float* g2  = (const float*)d_in[9];
    const float* be2 = (const float*)d_in[10];
    const float* m2  = (const float*)d_in[11];
    const float* v2  = (const float*)d_in[12];
    const float* w3  = (const float*)d_in[13];
    const float* b3  = (const float*)d_in[14];
    const float* g3  = (const float*)d_in[15];
    const float* be3 = (const float*)d_in[16];
    const float* m3  = (const float*)d_in[17];
    const float* v3  = (const float*)d_in[18];
    const float* wf  = (const float*)d_in[19];
    const float* bf  = (const float*)d_in[20];

    // workspace layout (bytes):
    //   ypool  bf16 [300][256][96]  @ 0          (14,745,600)
    //   zbuf   f32  [300][256]      @ 14,745,600 (307,200)
    //   Wbh    bf16 [320][104]      @ 15,052,800 (66,560)
    //   Wbl    bf16 [320][104]      @ 15,119,360 (66,560)
    //   xc     u32  [256][4][608]   @ 15,185,920 (2,490,368)
    //   s1c1   f32x2 [304]          @ 17,676,288 (2,432)
    unsigned short* ypool = (unsigned short*)d_ws;
    float* zbuf = (float*)((char*)d_ws + 14745600);
    unsigned short* Wbh = (unsigned short*)((char*)d_ws + 15052800);
    unsigned short* Wbl = (unsigned short*)((char*)d_ws + 15119360);
    unsigned int*   xc  = (unsigned int*)((char*)d_ws + 15185920);
    float2*         sc1 = (float2*)((char*)d_ws + 17676288);

    const int prep_elems = WBROWS * WROW + BATCH * 4 * LIN + MTN * 16;
    k_prep<<<(prep_elems + 255) / 256, 256, 0, stream>>>(
        w1, x, b1, g1, be1, m1, v1, Wbh, Wbl, xc, sc1);

    dim3 gc(BATCH, 6);
    k_conv7d<<<gc, 256, 0, stream>>>(Wbh, Wbl, xc, sc1, ypool);

    dim3 gm(NU, BATCH / BH);
    k_mlp<<<gm, 256, 0, stream>>>(ypool, w2, b2, g2, be2, m2, v2,
                                  w3, b3, g3, be3, m3, v3, zbuf);

    dim3 gf(NCLS, 4);
    k_final<<<gf, 256, 0, stream>>>(zbuf, wf, bf, (float*)d_out);
}